// Round 1
// baseline (427.392 us; speedup 1.0000x reference)
//
#include <hip/hip_runtime.h>
#include <cmath>

#define BB 512
#define VV 128
#define DD 256
#define HH 4
#define DHH 64

// ---------------- K1: Wx = x @ W^T ----------------
// M = B*V = 65536, N = D = 256, K = D = 256.
// 128x128 block tile, 256 threads (16x16), 8x8 per thread, K-tile 16.
// LDS layout [kk][row] stride 132 (16B-aligned, write 2-way / read A conflict-free,
// read B 4-way on b128 — acceptable, VALU-bound anyway).
__global__ __launch_bounds__(256, 2) void k_gemm(const float* __restrict__ x,
                                                 const float* __restrict__ Wm,
                                                 float* __restrict__ Wx) {
    __shared__ float As[16 * 132];
    __shared__ float Bs[16 * 132];
    const int t  = threadIdx.x;
    const int tc = t & 15, tr = t >> 4;
    const int r0 = blockIdx.x * 128;
    const int c0 = blockIdx.y * 128;
    float acc[8][8] = {};
    for (int k0 = 0; k0 < DD; k0 += 16) {
        #pragma unroll
        for (int p = 0; p < 8; ++p) {
            int e  = p * 256 + t;          // 0..2047
            int kk = e & 15, rr = e >> 4;  // kk 0..15, rr 0..127
            As[kk * 132 + rr] = x[(size_t)(r0 + rr) * DD + k0 + kk];
            Bs[kk * 132 + rr] = Wm[(size_t)(c0 + rr) * DD + k0 + kk];
        }
        __syncthreads();
        #pragma unroll
        for (int kk = 0; kk < 16; ++kk) {
            float av[8], bv[8];
            *(float4*)&av[0] = *(const float4*)&As[kk * 132 + tr * 8];
            *(float4*)&av[4] = *(const float4*)&As[kk * 132 + tr * 8 + 4];
            *(float4*)&bv[0] = *(const float4*)&Bs[kk * 132 + tc * 8];
            *(float4*)&bv[4] = *(const float4*)&Bs[kk * 132 + tc * 8 + 4];
            #pragma unroll
            for (int i = 0; i < 8; ++i)
                #pragma unroll
                for (int j = 0; j < 8; ++j)
                    acc[i][j] = fmaf(av[i], bv[j], acc[i][j]);
        }
        __syncthreads();
    }
    #pragma unroll
    for (int i = 0; i < 8; ++i) {
        int r = r0 + tr * 8 + i;
        float* dst = Wx + (size_t)r * DD + c0 + tc * 8;
        *(float4*)dst       = *(float4*)&acc[i][0];
        *(float4*)(dst + 4) = *(float4*)&acc[i][4];
    }
}

// ---------------- K2: ef[h][i][j] = edge_attr[i,j,:] . Ew[h,:] ----------------
__global__ void k_ef(const float* __restrict__ ea, const float* __restrict__ Ew,
                     float* __restrict__ efw) {
    int idx = blockIdx.x * 256 + threadIdx.x;  // h*V*V + i*V + j
    int h  = idx >> 14;                        // V*V = 16384
    int ij = idx & 16383;
    efw[idx] = ea[ij * 2] * Ew[h * 2] + ea[ij * 2 + 1] * Ew[h * 2 + 1];
}

// ---------------- K3: s_src/s_dst = Wx . a_src / a_dst ----------------
// One wave per (b,v,h) flat index wid; lane l holds Wx[wid*64+l].
__global__ __launch_bounds__(256) void k_scores(const float* __restrict__ Wx,
                                                const float* __restrict__ a,
                                                float* __restrict__ s_src,
                                                float* __restrict__ s_dst) {
    int wid  = blockIdx.x * 4 + (threadIdx.x >> 6);
    int lane = threadIdx.x & 63;
    float w  = Wx[(size_t)wid * 64 + lane];
    float ps = w * a[lane];
    float pd = w * a[64 + lane];
    #pragma unroll
    for (int off = 32; off > 0; off >>= 1) {
        ps += __shfl_down(ps, off);
        pd += __shfl_down(pd, off);
    }
    if (lane == 0) {
        s_src[wid] = ps;
        s_dst[wid] = pd;
    }
}

// ---------------- K4: attention + softmax(axis=i) + aggregation + ELU + mask ----
// One block per (b,h). LDS: Wx[b,:,h,:] 32KB + alpha tile 128x32 16KB + small.
__global__ __launch_bounds__(256, 2) void k_attn(
    const float* __restrict__ Wx, const float* __restrict__ s_src,
    const float* __restrict__ s_dst, const float* __restrict__ efw,
    const int* __restrict__ adj, const int* __restrict__ mask,
    float* __restrict__ out) {
    __shared__ float wx_l[VV * DHH];   // 32 KB
    __shared__ float al[VV * 32];      // 16 KB (p/alpha tile for 32 j's)
    __shared__ float ss[VV], sdl[VV];
    __shared__ int   mk[VV];
    __shared__ float red[8 * 32];
    __shared__ float mcol[32], rden[32];

    const int t = threadIdx.x;
    const int b = blockIdx.x >> 2;
    const int h = blockIdx.x & 3;

    // Stage Wx[b, :, h, :] (128 x 64 fp32)
    #pragma unroll
    for (int p = 0; p < 8; ++p) {
        int idx4 = p * 256 + t;           // 0..2047 float4 index
        int i = idx4 >> 4, d4 = idx4 & 15;
        float4 v = *(const float4*)(Wx + (size_t)(b * VV + i) * DD + h * DHH + d4 * 4);
        *(float4*)(wx_l + i * DHH + d4 * 4) = v;
    }
    if (t < VV) {
        int wid = (b * VV + t) * HH + h;
        ss[t]  = s_src[wid];
        sdl[t] = s_dst[wid];
        mk[t]  = mask[b * VV + t];
    }
    __syncthreads();

    const float* efh = efw + h * VV * VV;
    const int tj = t & 31, ti = t >> 5;     // phase A: 32 j's x 8 i-chunks
    const int tdd = t & 15, tjo = t >> 4;   // phase B: 16 d4's x 16 j-pairs

    for (int jt = 0; jt < 4; ++jt) {
        // ---- Phase A: scores + softmax over i for 32 columns ----
        const int j = jt * 32 + tj;
        const bool colv = (mk[j] == 0);
        const float sdj = sdl[j];
        float ev[16];
        float mx = -INFINITY;
        #pragma unroll
        for (int ii = 0; ii < 16; ++ii) {
            int i = ti * 16 + ii;
            float e = -INFINITY;
            if (colv && mk[i] == 0 && adj[i * VV + j] != 0) {
                e = ss[i] + sdj + efh[i * VV + j];
                e = e >= 0.f ? e : 0.2f * e;   // leaky relu
                mx = fmaxf(mx, e);
            }
            ev[ii] = e;
        }
        red[ti * 32 + tj] = mx;
        __syncthreads();
        if (ti == 0) {
            float m = red[tj];
            #pragma unroll
            for (int k = 1; k < 8; ++k) m = fmaxf(m, red[k * 32 + tj]);
            mcol[tj] = (m > -3.0e38f) ? m : 0.f;   // all-invalid column -> 0
        }
        __syncthreads();
        const float m = mcol[tj];
        float psum = 0.f;
        #pragma unroll
        for (int ii = 0; ii < 16; ++ii) {
            float p = __expf(ev[ii] - m);   // exp(-inf) = 0 for invalid
            al[(ti * 16 + ii) * 32 + tj] = p;
            psum += p;
        }
        red[ti * 32 + tj] = psum;
        __syncthreads();
        if (ti == 0) {
            float s = red[tj];
            #pragma unroll
            for (int k = 1; k < 8; ++k) s += red[k * 32 + tj];
            rden[tj] = (s > 0.f) ? 1.f / s : 0.f;  // denom==0 -> alpha=0
        }
        __syncthreads();
        const float r = rden[tj];
        #pragma unroll
        for (int ii = 0; ii < 16; ++ii)
            al[(ti * 16 + ii) * 32 + tj] *= r;
        __syncthreads();

        // ---- Phase B: out[j, d] = sum_i alpha[i,j] * wx[i,d], ELU, store ----
        float4 a0 = {0, 0, 0, 0}, a1 = {0, 0, 0, 0};
        const int jb = jt * 32 + tjo * 2;
        for (int i = 0; i < VV; ++i) {
            float p0 = al[i * 32 + tjo * 2];
            float p1 = al[i * 32 + tjo * 2 + 1];
            float4 w4 = *(const float4*)(wx_l + i * DHH + tdd * 4);
            a0.x = fmaf(p0, w4.x, a0.x); a0.y = fmaf(p0, w4.y, a0.y);
            a0.z = fmaf(p0, w4.z, a0.z); a0.w = fmaf(p0, w4.w, a0.w);
            a1.x = fmaf(p1, w4.x, a1.x); a1.y = fmaf(p1, w4.y, a1.y);
            a1.z = fmaf(p1, w4.z, a1.z); a1.w = fmaf(p1, w4.w, a1.w);
        }
        float4 o0, o1;
        o0.x = a0.x > 0.f ? a0.x : expm1f(a0.x);
        o0.y = a0.y > 0.f ? a0.y : expm1f(a0.y);
        o0.z = a0.z > 0.f ? a0.z : expm1f(a0.z);
        o0.w = a0.w > 0.f ? a0.w : expm1f(a0.w);
        o1.x = a1.x > 0.f ? a1.x : expm1f(a1.x);
        o1.y = a1.y > 0.f ? a1.y : expm1f(a1.y);
        o1.z = a1.z > 0.f ? a1.z : expm1f(a1.z);
        o1.w = a1.w > 0.f ? a1.w : expm1f(a1.w);
        // masked columns: alpha==0 everywhere -> acc==0 -> elu(0)==0 == required 0
        float* dst0 = out + (size_t)(b * VV + jb) * DD + h * DHH + tdd * 4;
        *(float4*)dst0        = o0;
        *(float4*)(dst0 + DD) = o1;
        __syncthreads();   // al reused next jt
    }
}

extern "C" void kernel_launch(void* const* d_in, const int* in_sizes, int n_in,
                              void* d_out, int out_size, void* d_ws, size_t ws_size,
                              hipStream_t stream) {
    const float* x    = (const float*)d_in[0];
    const int*   adj  = (const int*)d_in[1];
    const float* ea   = (const float*)d_in[2];
    const int*   mask = (const int*)d_in[3];
    const float* Wm   = (const float*)d_in[4];
    const float* a    = (const float*)d_in[5];
    const float* Ew   = (const float*)d_in[6];
    float* out = (float*)d_out;

    // Workspace layout (fp32): Wx 64MB, s_src 1MB, s_dst 1MB, ef 0.25MB
    float* Wx    = (float*)d_ws;
    float* s_src = Wx + (size_t)BB * VV * DD;
    float* s_dst = s_src + (size_t)BB * VV * HH;
    float* efw   = s_dst + (size_t)BB * VV * HH;

    k_gemm<<<dim3(BB * VV / 128, DD / 128), 256, 0, stream>>>(x, Wm, Wx);
    k_ef<<<HH * VV * VV / 256, 256, 0, stream>>>(ea, Ew, efw);
    k_scores<<<BB * VV * HH / 4, 256, 0, stream>>>(Wx, a, s_src, s_dst);
    k_attn<<<BB * HH, 256, 0, stream>>>(Wx, s_src, s_dst, efw, adj, mask, out);
}

// Round 2
// 168.461 us; speedup vs baseline: 2.5370x; 2.5370x over previous
//
#include <hip/hip_runtime.h>
#include <cmath>

#define BB 512
#define VV 128
#define DD 256
#define HH 4
#define DHH 64

typedef unsigned short u16;
typedef __attribute__((ext_vector_type(8))) short bf16x8;
typedef __attribute__((ext_vector_type(4))) short bf16x4;
typedef __attribute__((ext_vector_type(4))) float f32x4;

__device__ __forceinline__ u16 f2bf(float f) {
    unsigned u = __builtin_bit_cast(unsigned, f);
    u = (u + 0x7fffu + ((u >> 16) & 1u)) >> 16;
    return (u16)u;
}

// ---------------- K1: efm[h][i][j] = adj ? edge_attr[i,j,:].Ew[h,:] : -inf ----
__global__ void k_ef(const float* __restrict__ ea, const float* __restrict__ Ew,
                     const int* __restrict__ adj, float* __restrict__ efm) {
    int idx = blockIdx.x * 256 + threadIdx.x;   // h*16384 + i*128 + j
    int hh = idx >> 14, ij = idx & 16383;
    float v = -INFINITY;
    if (adj[ij])
        v = fmaf(ea[ij * 2 + 1], Ew[hh * 2 + 1], ea[ij * 2] * Ew[hh * 2]);
    efm[idx] = v;
}

// ---------------- K2: Wx = x @ W^T via bf16 MFMA; writes WxT[b][h][d][v] bf16
// and fused s_src/s_dst (fp32). M-block = one b (128 rows), N-block = 128 cols.
// 4 waves in 2x2; each wave 64x64 via 4x4 grid of 16x16x32 mfma; BK=32.
__global__ __launch_bounds__(256, 2) void k_gemm(
    const float* __restrict__ x, const float* __restrict__ Wm,
    const float* __restrict__ a, u16* __restrict__ WxT,
    float* __restrict__ s_src, float* __restrict__ s_dst) {
    __shared__ u16 As[128 * 32];   // [row][k] bf16, 8KB
    __shared__ u16 Bs[128 * 32];

    const int t = threadIdx.x;
    const int w = t >> 6, L = t & 63;
    const int wr = w >> 1, wc = w & 1;
    const int lr = L & 15, lg = L >> 4;
    const int b  = blockIdx.x;
    const int c0 = blockIdx.y * 128;
    const int row = t >> 1, seg = t & 1;   // staging: 2 threads/row, 16 elems each

    f32x4 acc[4][4];
    #pragma unroll
    for (int i = 0; i < 4; ++i)
        #pragma unroll
        for (int j = 0; j < 4; ++j) acc[i][j] = (f32x4){0.f, 0.f, 0.f, 0.f};

    const float* xrow = x  + (size_t)(b * 128 + row) * DD + seg * 16;
    const float* wrow = Wm + (size_t)(c0 + row) * DD + seg * 16;
    u16* adst = &As[row * 32 + seg * 16];
    u16* bdst = &Bs[row * 32 + seg * 16];

    for (int k0 = 0; k0 < DD; k0 += 32) {
        float4 f0 = *(const float4*)(xrow + k0);
        float4 f1 = *(const float4*)(xrow + k0 + 4);
        float4 f2 = *(const float4*)(xrow + k0 + 8);
        float4 f3 = *(const float4*)(xrow + k0 + 12);
        float4 g0 = *(const float4*)(wrow + k0);
        float4 g1 = *(const float4*)(wrow + k0 + 4);
        float4 g2 = *(const float4*)(wrow + k0 + 8);
        float4 g3 = *(const float4*)(wrow + k0 + 12);
        bf16x8 pa, pb, qa, qb;
        pa[0]=(short)f2bf(f0.x); pa[1]=(short)f2bf(f0.y); pa[2]=(short)f2bf(f0.z); pa[3]=(short)f2bf(f0.w);
        pa[4]=(short)f2bf(f1.x); pa[5]=(short)f2bf(f1.y); pa[6]=(short)f2bf(f1.z); pa[7]=(short)f2bf(f1.w);
        pb[0]=(short)f2bf(f2.x); pb[1]=(short)f2bf(f2.y); pb[2]=(short)f2bf(f2.z); pb[3]=(short)f2bf(f2.w);
        pb[4]=(short)f2bf(f3.x); pb[5]=(short)f2bf(f3.y); pb[6]=(short)f2bf(f3.z); pb[7]=(short)f2bf(f3.w);
        qa[0]=(short)f2bf(g0.x); qa[1]=(short)f2bf(g0.y); qa[2]=(short)f2bf(g0.z); qa[3]=(short)f2bf(g0.w);
        qa[4]=(short)f2bf(g1.x); qa[5]=(short)f2bf(g1.y); qa[6]=(short)f2bf(g1.z); qa[7]=(short)f2bf(g1.w);
        qb[0]=(short)f2bf(g2.x); qb[1]=(short)f2bf(g2.y); qb[2]=(short)f2bf(g2.z); qb[3]=(short)f2bf(g2.w);
        qb[4]=(short)f2bf(g3.x); qb[5]=(short)f2bf(g3.y); qb[6]=(short)f2bf(g3.z); qb[7]=(short)f2bf(g3.w);
        *(bf16x8*)adst       = pa;
        *(bf16x8*)(adst + 8) = pb;
        *(bf16x8*)bdst       = qa;
        *(bf16x8*)(bdst + 8) = qb;
        __syncthreads();

        bf16x8 af[4], bfr[4];
        #pragma unroll
        for (int mi = 0; mi < 4; ++mi)
            af[mi] = *(const bf16x8*)&As[(wr * 64 + mi * 16 + lr) * 32 + lg * 8];
        #pragma unroll
        for (int ni = 0; ni < 4; ++ni)
            bfr[ni] = *(const bf16x8*)&Bs[(wc * 64 + ni * 16 + lr) * 32 + lg * 8];
        #pragma unroll
        for (int mi = 0; mi < 4; ++mi)
            #pragma unroll
            for (int ni = 0; ni < 4; ++ni)
                acc[mi][ni] = __builtin_amdgcn_mfma_f32_16x16x32_bf16(
                    af[mi], bfr[ni], acc[mi][ni], 0, 0, 0);
        __syncthreads();
    }

    // Epilogue: C[m=v][n=c]; col = lr, row = lg*4+reg within 16x16 tile.
    const int h = blockIdx.y * 2 + wc;
    float as_[4], ad_[4];
    #pragma unroll
    for (int ni = 0; ni < 4; ++ni) {
        as_[ni] = a[ni * 16 + lr];
        ad_[ni] = a[64 + ni * 16 + lr];
    }
    float ps[16], pd[16];
    #pragma unroll
    for (int k = 0; k < 16; ++k) { ps[k] = 0.f; pd[k] = 0.f; }

    #pragma unroll
    for (int mi = 0; mi < 4; ++mi) {
        #pragma unroll
        for (int ni = 0; ni < 4; ++ni) {
            int d  = ni * 16 + lr;
            int vb = wr * 64 + mi * 16 + lg * 4;
            bf16x4 o;
            #pragma unroll
            for (int r = 0; r < 4; ++r) {
                float v = acc[mi][ni][r];
                o[r] = (short)f2bf(v);
                ps[mi * 4 + r] = fmaf(v, as_[ni], ps[mi * 4 + r]);
                pd[mi * 4 + r] = fmaf(v, ad_[ni], pd[mi * 4 + r]);
            }
            *(bf16x4*)&WxT[(((size_t)b * HH + h) * DHH + d) * VV + vb] = o;
        }
    }
    // reduce s partials across the 16 lanes sharing each v
    #pragma unroll
    for (int k = 0; k < 16; ++k) {
        #pragma unroll
        for (int m = 1; m < 16; m <<= 1) {
            ps[k] += __shfl_xor(ps[k], m);
            pd[k] += __shfl_xor(pd[k], m);
        }
    }
    if (lr == 0) {
        #pragma unroll
        for (int mi = 0; mi < 4; ++mi)
            #pragma unroll
            for (int r = 0; r < 4; ++r) {
                int v = wr * 64 + mi * 16 + lg * 4 + r;
                s_src[((size_t)b * VV + v) * HH + h] = ps[mi * 4 + r];
                s_dst[((size_t)b * VV + v) * HH + h] = pd[mi * 4 + r];
            }
    }
}

// ---------------- K3: attention, one block per (b,h) ----------------
// Phase A: p[i,j] = exp(leaky(ss[i]+sd[j]+efm[h,i,j])) unnormalized (no max
// pass: |e| <~ 10, fp32-safe; masks arrive as -inf -> p=0). Store bf16 in
// alT[j][i] (A-fragment layout). Phase B: C[j,d] = sum_i alT[j][i]*WxT[d][i]
// via mfma, scale by 1/denom in epilogue, ELU, store.
__global__ __launch_bounds__(256, 4) void k_attn(
    const u16* __restrict__ WxT, const float* __restrict__ s_src,
    const float* __restrict__ s_dst, const float* __restrict__ efm,
    const int* __restrict__ mask, float* __restrict__ out) {
    __shared__ u16 alT[128 * 136];   // [j][i], pad +8 bf16: 16B-aligned rows, 2-way banks
    __shared__ float ssl[128], sdl[128], red[256], rden[128];

    const int t = threadIdx.x;
    const int b = blockIdx.x >> 2, h = blockIdx.x & 3;

    if (t < 128) {
        int mk = mask[b * VV + t];
        float vs = s_src[((size_t)b * VV + t) * HH + h];
        float vd = s_dst[((size_t)b * VV + t) * HH + h];
        ssl[t] = mk ? -INFINITY : vs;
        sdl[t] = mk ? -INFINITY : vd;
    }
    __syncthreads();

    const int j = t & 127, half = t >> 7;
    const float sdj = sdl[j];
    const float* efh = efm + ((size_t)h * VV + half * 64) * VV + j;
    float psum = 0.f;
    for (int i8 = 0; i8 < 64; i8 += 8) {
        bf16x8 pk;
        #pragma unroll
        for (int u = 0; u < 8; ++u) {
            int i = half * 64 + i8 + u;
            float e = ssl[i] + sdj + efh[(size_t)(i8 + u) * VV];
            e = e >= 0.f ? e : 0.2f * e;
            float p = __expf(e);     // exp(-inf) = 0 handles all masking
            psum += p;
            pk[u] = (short)f2bf(p);
        }
        *(bf16x8*)&alT[j * 136 + half * 64 + i8] = pk;
    }
    red[half * 128 + j] = psum;
    __syncthreads();
    if (half == 0) {
        float s = red[j] + red[128 + j];
        rden[j] = s > 0.f ? 1.f / s : 0.f;
    }
    __syncthreads();

    // Phase B: wave w handles j-tiles {2w, 2w+1}, all 4 d-tiles. K = 128 (i).
    const int w = t >> 6, L = t & 63;
    const int lr = L & 15, lg = L >> 4;
    const u16* gB = WxT + ((size_t)b * HH + h) * DHH * VV;   // [d][i]
    f32x4 acc[2][4];
    #pragma unroll
    for (int mi = 0; mi < 2; ++mi)
        #pragma unroll
        for (int ni = 0; ni < 4; ++ni) acc[mi][ni] = (f32x4){0.f, 0.f, 0.f, 0.f};

    #pragma unroll
    for (int ks = 0; ks < 4; ++ks) {
        const int kk = ks * 32 + lg * 8;
        bf16x8 bfr[4];
        #pragma unroll
        for (int ni = 0; ni < 4; ++ni)
            bfr[ni] = *(const bf16x8*)(gB + (size_t)(ni * 16 + lr) * VV + kk);
        #pragma unroll
        for (int mi = 0; mi < 2; ++mi) {
            bf16x8 af = *(const bf16x8*)&alT[(w * 32 + mi * 16 + lr) * 136 + kk];
            #pragma unroll
            for (int ni = 0; ni < 4; ++ni)
                acc[mi][ni] = __builtin_amdgcn_mfma_f32_16x16x32_bf16(
                    af, bfr[ni], acc[mi][ni], 0, 0, 0);
        }
    }

    #pragma unroll
    for (int mi = 0; mi < 2; ++mi)
        #pragma unroll
        for (int ni = 0; ni < 4; ++ni) {
            int dcol = ni * 16 + lr;
            int jb   = w * 32 + mi * 16 + lg * 4;
            float* op = out + ((size_t)b * VV + jb) * DD + h * DHH + dcol;
            #pragma unroll
            for (int r = 0; r < 4; ++r) {
                float v = acc[mi][ni][r] * rden[jb + r];
                v = v > 0.f ? v : expm1f(v);   // ELU; masked j: rden=0 -> 0
                op[(size_t)r * DD] = v;
            }
        }
}

extern "C" void kernel_launch(void* const* d_in, const int* in_sizes, int n_in,
                              void* d_out, int out_size, void* d_ws, size_t ws_size,
                              hipStream_t stream) {
    const float* x    = (const float*)d_in[0];
    const int*   adj  = (const int*)d_in[1];
    const float* ea   = (const float*)d_in[2];
    const int*   mask = (const int*)d_in[3];
    const float* Wm   = (const float*)d_in[4];
    const float* a    = (const float*)d_in[5];
    const float* Ew   = (const float*)d_in[6];
    float* out = (float*)d_out;

    // ws: WxT bf16 32MiB | s_src 1MiB | s_dst 1MiB | efm 256KiB  (~34.25MiB)
    u16*   WxT   = (u16*)d_ws;
    float* s_src = (float*)(WxT + (size_t)BB * HH * DHH * VV);
    float* s_dst = s_src + (size_t)BB * VV * HH;
    float* efm   = s_dst + (size_t)BB * VV * HH;

    k_ef<<<HH * VV * VV / 256, 256, 0, stream>>>(ea, Ew, adj, efm);
    k_gemm<<<dim3(BB, 2), 256, 0, stream>>>(x, Wm, a, WxT, s_src, s_dst);
    k_attn<<<BB * HH, 256, 0, stream>>>(WxT, s_src, s_dst, efm, mask, out);
}

// Round 4
// 166.308 us; speedup vs baseline: 2.5699x; 1.0129x over previous
//
#include <hip/hip_runtime.h>
#include <cmath>

#define BB 512
#define VV 128
#define DD 256
#define HH 4
#define DHH 64

typedef unsigned short u16;
typedef __attribute__((ext_vector_type(8))) short bf16x8;
typedef __attribute__((ext_vector_type(4))) short bf16x4;
typedef __attribute__((ext_vector_type(4))) float f32x4;

__device__ __forceinline__ u16 f2bf(float f) {
    unsigned u = __builtin_bit_cast(unsigned, f);
    u = (u + 0x7fffu + ((u >> 16) & 1u)) >> 16;
    return (u16)u;
}
__device__ __forceinline__ unsigned pk2(float a, float b) {
    return (unsigned)f2bf(a) | ((unsigned)f2bf(b) << 16);
}

// ---------------- K1: efm[h][i][j] = adj ? edge_attr[i,j,:].Ew[h,:] : -inf ----
__global__ void k_ef(const float* __restrict__ ea, const float* __restrict__ Ew,
                     const int* __restrict__ adj, float* __restrict__ efm) {
    int idx = blockIdx.x * 256 + threadIdx.x;   // h*16384 + i*128 + j
    int hh = idx >> 14, ij = idx & 16383;
    float v = -INFINITY;
    if (adj[ij])
        v = fmaf(ea[ij * 2 + 1], Ew[hh * 2 + 1], ea[ij * 2] * Ew[hh * 2]);
    efm[idx] = v;
}

// ---------------- K2: fully fused GAT per (b, head-pair) ----------------
// Block = (b, hp). GEMM: C[v][c] = x[b] @ W^T slice (128x128, K=256) via bf16
// MFMA, 4 waves 2x2. Epilogue -> WxL[c][v] bf16 in LDS + fused s_src/s_dst
// (masked with -inf). Then per local head: P = exp(leaky(ss+sd+efm))
// unnormalized bf16 -> alT[j][i]; PV via MFMA; scale 1/denom, ELU, store.
__global__ __launch_bounds__(256, 2) void k_fused(
    const float* __restrict__ x, const float* __restrict__ Wm,
    const float* __restrict__ a, const float* __restrict__ efm,
    const int* __restrict__ mask, float* __restrict__ out) {
    __shared__ u16 WxL[128 * 136];      // [c][v], 34.8 KB
    __shared__ u16 scratch[128 * 136];  // As/Bs in GEMM; alT in attention
    __shared__ float ssl[256], sdl[256], red[256], rden[128];
    __shared__ int mkl[128];

    u16* As = scratch;                  // [128][40]
    u16* Bs = scratch + 128 * 40;       // [128][40]
    u16* alT = scratch;                 // [128][136]

    const int t = threadIdx.x;
    const int b = blockIdx.x, hp = blockIdx.y;
    const int w = t >> 6, L = t & 63;
    const int wr = w >> 1, wc = w & 1;
    const int lr = L & 15, lg = L >> 4;

    if (t < 128) mkl[t] = mask[b * VV + t];

    // ---- GEMM phase ----
    const int row = t >> 1, seg = t & 1;
    const float* xs = x  + ((size_t)b * VV + row) * DD + seg * 16;
    const float* ws = Wm + ((size_t)(hp * 128 + row)) * DD + seg * 16;
    u16* adst = As + row * 40 + seg * 16;
    u16* bdst = Bs + row * 40 + seg * 16;

    f32x4 acc[4][4];
    #pragma unroll
    for (int i = 0; i < 4; ++i)
        #pragma unroll
        for (int j = 0; j < 4; ++j) acc[i][j] = (f32x4){0.f, 0.f, 0.f, 0.f};

    float4 px[4], pw[4];
    #pragma unroll
    for (int q = 0; q < 4; ++q) {
        px[q] = *(const float4*)(xs + q * 4);
        pw[q] = *(const float4*)(ws + q * 4);
    }

    for (int ks = 0; ks < 8; ++ks) {
        bf16x8 va, vb, qa, qb;
        unsigned* vap = (unsigned*)&va; unsigned* vbp = (unsigned*)&vb;
        unsigned* qap = (unsigned*)&qa; unsigned* qbp = (unsigned*)&qb;
        vap[0] = pk2(px[0].x, px[0].y); vap[1] = pk2(px[0].z, px[0].w);
        vap[2] = pk2(px[1].x, px[1].y); vap[3] = pk2(px[1].z, px[1].w);
        vbp[0] = pk2(px[2].x, px[2].y); vbp[1] = pk2(px[2].z, px[2].w);
        vbp[2] = pk2(px[3].x, px[3].y); vbp[3] = pk2(px[3].z, px[3].w);
        qap[0] = pk2(pw[0].x, pw[0].y); qap[1] = pk2(pw[0].z, pw[0].w);
        qap[2] = pk2(pw[1].x, pw[1].y); qap[3] = pk2(pw[1].z, pw[1].w);
        qbp[0] = pk2(pw[2].x, pw[2].y); qbp[1] = pk2(pw[2].z, pw[2].w);
        qbp[2] = pk2(pw[3].x, pw[3].y); qbp[3] = pk2(pw[3].z, pw[3].w);
        *(bf16x8*)adst       = va;
        *(bf16x8*)(adst + 8) = vb;
        *(bf16x8*)bdst       = qa;
        *(bf16x8*)(bdst + 8) = qb;
        __syncthreads();
        if (ks < 7) {   // prefetch next K-tile; overlaps with MFMAs below
            #pragma unroll
            for (int q = 0; q < 4; ++q) {
                px[q] = *(const float4*)(xs + (ks + 1) * 32 + q * 4);
                pw[q] = *(const float4*)(ws + (ks + 1) * 32 + q * 4);
            }
        }
        bf16x8 af[4], bfr[4];
        #pragma unroll
        for (int mi = 0; mi < 4; ++mi)
            af[mi] = *(const bf16x8*)&As[(wr * 64 + mi * 16 + lr) * 40 + lg * 8];
        #pragma unroll
        for (int ni = 0; ni < 4; ++ni)
            bfr[ni] = *(const bf16x8*)&Bs[(wc * 64 + ni * 16 + lr) * 40 + lg * 8];
        #pragma unroll
        for (int mi = 0; mi < 4; ++mi)
            #pragma unroll
            for (int ni = 0; ni < 4; ++ni)
                acc[mi][ni] = __builtin_amdgcn_mfma_f32_16x16x32_bf16(
                    af[mi], bfr[ni], acc[mi][ni], 0, 0, 0);
        __syncthreads();
    }

    // ---- GEMM epilogue: WxL[c][v] bf16 + fused scores ----
    float as_[4], ad_[4];
    #pragma unroll
    for (int ni = 0; ni < 4; ++ni) {
        as_[ni] = a[ni * 16 + lr];        // d-within-head = ni*16+lr
        ad_[ni] = a[64 + ni * 16 + lr];
    }
    float ps[16], pd[16];
    #pragma unroll
    for (int k = 0; k < 16; ++k) { ps[k] = 0.f; pd[k] = 0.f; }
    #pragma unroll
    for (int mi = 0; mi < 4; ++mi) {
        #pragma unroll
        for (int ni = 0; ni < 4; ++ni) {
            const int c  = wc * 64 + ni * 16 + lr;      // local column (hl*64+d)
            const int vb = wr * 64 + mi * 16 + lg * 4;
            bf16x4 o;
            #pragma unroll
            for (int r = 0; r < 4; ++r) {
                float v = acc[mi][ni][r];
                o[r] = (short)f2bf(v);
                ps[mi * 4 + r] = fmaf(v, as_[ni], ps[mi * 4 + r]);
                pd[mi * 4 + r] = fmaf(v, ad_[ni], pd[mi * 4 + r]);
            }
            *(bf16x4*)&WxL[c * 136 + vb] = o;
        }
    }
    #pragma unroll
    for (int k = 0; k < 16; ++k) {
        #pragma unroll
        for (int m = 1; m < 16; m <<= 1) {
            ps[k] += __shfl_xor(ps[k], m);
            pd[k] += __shfl_xor(pd[k], m);
        }
    }
    if (lr == 0) {
        #pragma unroll
        for (int mi = 0; mi < 4; ++mi)
            #pragma unroll
            for (int r = 0; r < 4; ++r) {
                int v = wr * 64 + mi * 16 + lg * 4 + r;
                bool mk = mkl[v] != 0;
                ssl[wc * 128 + v] = mk ? -INFINITY : ps[mi * 4 + r];
                sdl[wc * 128 + v] = mk ? -INFINITY : pd[mi * 4 + r];
            }
    }
    __syncthreads();   // WxL + scores ready; As/Bs dead -> alT may reuse

    // ---- Attention: two local heads ----
    const int j = t & 127, half = t >> 7;
    for (int hl = 0; hl < 2; ++hl) {
        const int h = hp * 2 + hl;
        const float sdj = sdl[hl * 128 + j];
        const float* efh = efm + ((size_t)h * VV + half * 64) * VV + j;
        u16* alrow = alT + j * 136 + half * 64;
        float psum = 0.f;
        for (int i8 = 0; i8 < 64; i8 += 8) {
            bf16x8 pk;
            #pragma unroll
            for (int u = 0; u < 8; ++u) {
                float e = ssl[hl * 128 + half * 64 + i8 + u] + sdj
                        + efh[(size_t)(i8 + u) * VV];
                e = e >= 0.f ? e : 0.2f * e;
                float p = __expf(e);       // exp(-inf)=0 handles all masking
                psum += p;
                pk[u] = (short)f2bf(p);
            }
            *(bf16x8*)(alrow + i8) = pk;
        }
        red[half * 128 + j] = psum;
        __syncthreads();
        if (half == 0) {
            float s = red[j] + red[128 + j];
            rden[j] = s > 0.f ? 1.f / s : 0.f;
        }
        __syncthreads();

        // PV: wave w -> j-tiles {2w,2w+1}; C2[j][d] = sum_i alT[j][i]*WxL[hl*64+d][i]
        f32x4 acc2[2][4];
        #pragma unroll
        for (int mi = 0; mi < 2; ++mi)
            #pragma unroll
            for (int ni = 0; ni < 4; ++ni) acc2[mi][ni] = (f32x4){0.f, 0.f, 0.f, 0.f};
        #pragma unroll
        for (int ks = 0; ks < 4; ++ks) {
            const int kk = ks * 32 + lg * 8;
            bf16x8 bfr2[4];
            #pragma unroll
            for (int ni = 0; ni < 4; ++ni)
                bfr2[ni] = *(const bf16x8*)&WxL[(hl * 64 + ni * 16 + lr) * 136 + kk];
            #pragma unroll
            for (int mi = 0; mi < 2; ++mi) {
                bf16x8 af2 = *(const bf16x8*)&alT[(w * 32 + mi * 16 + lr) * 136 + kk];
                #pragma unroll
                for (int ni = 0; ni < 4; ++ni)
                    acc2[mi][ni] = __builtin_amdgcn_mfma_f32_16x16x32_bf16(
                        af2, bfr2[ni], acc2[mi][ni], 0, 0, 0);
            }
        }
        #pragma unroll
        for (int mi = 0; mi < 2; ++mi)
            #pragma unroll
            for (int ni = 0; ni < 4; ++ni) {
                const int dcol = ni * 16 + lr;
                const int jb   = w * 32 + mi * 16 + lg * 4;
                float* op = out + ((size_t)b * VV + jb) * DD + h * DHH + dcol;
                #pragma unroll
                for (int r = 0; r < 4; ++r) {
                    float v = acc2[mi][ni][r] * rden[jb + r];
                    v = v > 0.f ? v : expm1f(v);   // ELU; masked/empty j -> 0
                    op[(size_t)r * DD] = v;
                }
            }
        __syncthreads();   // alT/red reused by next head
    }
}

extern "C" void kernel_launch(void* const* d_in, const int* in_sizes, int n_in,
                              void* d_out, int out_size, void* d_ws, size_t ws_size,
                              hipStream_t stream) {
    const float* x    = (const float*)d_in[0];
    const int*   adj  = (const int*)d_in[1];
    const float* ea   = (const float*)d_in[2];
    const int*   mask = (const int*)d_in[3];
    const float* Wm   = (const float*)d_in[4];
    const float* a    = (const float*)d_in[5];
    const float* Ew   = (const float*)d_in[6];
    float* out = (float*)d_out;

    float* efm = (float*)d_ws;   // [H][V][V] fp32, 256 KiB

    k_ef<<<HH * VV * VV / 256, 256, 0, stream>>>(ea, Ew, adj, efm);
    k_fused<<<dim3(BB, 2), 256, 0, stream>>>(x, Wm, a, efm, mask, out);
}